// Round 8
// baseline (241.505 us; speedup 1.0000x reference)
//
#include <hip/hip_runtime.h>
#include <hip/hip_bf16.h>

typedef __attribute__((ext_vector_type(8))) __bf16 bf16x8;
typedef __attribute__((ext_vector_type(4))) float f32x4;

#define N_NODES 50000
#define N_EDGES 800000
#define N_TILES 50000            // 16-edge tiles
#define WAVES 8                  // 512-thread blocks
#define TPW 4
#define TILES_PER_BLOCK (WAVES * TPW)   // 32

// ---- setup: W2^T -> bf16 in workspace (8 KB, L1-resident in main kernel) ----
__global__ void prep_w2(const float* __restrict__ W2, __bf16* __restrict__ wsW2) {
    int i = blockIdx.x * 256 + threadIdx.x;       // i = k*64 + n (k=n1, n=n2)
    if (i < 64 * 64) {
        int k = i >> 6, n = i & 63;
        wsW2[n * 64 + k] = (__bf16)W2[i];         // wsW2[n2][n1]
    }
}

__global__ __launch_bounds__(512, 6) void edge_mlp_kernel(
    const float* __restrict__ x_s, const float* __restrict__ x_t,
    const int* __restrict__ edge_index, const float* __restrict__ edge_attr,
    const float* __restrict__ u, const int* __restrict__ batch_e,
    const float* __restrict__ W1, const float* __restrict__ b1,
    const __bf16* __restrict__ wsW2, const float* __restrict__ b2,
    float* __restrict__ out)
{
    // LDS: 32768 + 8*2432 = 52224 B -> 3 blocks/CU -> 24 waves/CU
    __shared__ __align__(16) unsigned char sW1[32768];   // [n1][k] bf16, 512B rows, XOR-swz
    __shared__ __align__(16) __bf16 sH1[WAVES][16][76];  // [edge][n1], pad 76

    const int t = threadIdx.x;

    // ---- stage W1 bf16, XOR-swizzled (r5/r7-verified) ----
    for (int idx = t; idx < 256 * 64; idx += 512) {
        int k = idx >> 6, n = idx & 63;
        *(__bf16*)(sW1 + n * 512 + ((k * 2) ^ ((n & 7) << 4))) = (__bf16)W1[idx];
    }
    __syncthreads();

    const int wave = t >> 6;
    const int lane = t & 63;
    const int l15  = lane & 15;
    const int lk   = lane >> 4;
    const int wxor = (l15 & 7) << 4;

    // ---- bias registers (r4-verified) ----
    float bv1[4];
    #pragma unroll
    for (int nf = 0; nf < 4; ++nf) bv1[nf] = b1[nf * 16 + l15];
    f32x4 bias2frag[4];
    #pragma unroll
    for (int mf = 0; mf < 4; ++mf)
        #pragma unroll
        for (int r = 0; r < 4; ++r)
            bias2frag[mf][r] = b2[mf * 16 + lk * 4 + r];

    const int tile_base = (blockIdx.x * WAVES + wave) * TPW;

    // ---- preload indices for this wave's tiles (guarded) ----
    int srcs[TPW], tgts[TPW], bgs[TPW];
    #pragma unroll
    for (int i = 0; i < TPW; ++i) {
        const int tile = tile_base + i;
        if (tile < N_TILES) {
            const int e = tile * 16 + l15;
            srcs[i] = edge_index[e];
            tgts[i] = edge_index[N_EDGES + e];
            bgs[i]  = batch_e[e];
        } else { srcs[i] = 0; tgts[i] = 0; bgs[i] = 0; }
    }

    for (int i = 0; i < TPW; ++i) {
        const int tile = tile_base + i;
        if (tile >= N_TILES) break;
        const int e = tile * 16 + l15;

        const float* seg0 = x_s + (long long)srcs[i] * 64;
        const float* seg1 = x_t + (long long)tgts[i] * 64;
        const float* seg2 = edge_attr + (long long)e * 64;
        const float* seg3 = u + (long long)bgs[i] * 64;

        // ---- GEMM1 (r2 structure): gather -> cvt -> MFMA, bias folded ----
        f32x4 acc[4];
        #pragma unroll
        for (int nf = 0; nf < 4; ++nf)
            acc[nf] = (f32x4){bv1[nf], bv1[nf], bv1[nf], bv1[nf]};
        #pragma unroll
        for (int kk = 0; kk < 8; ++kk) {
            const int k0 = kk * 32 + lk * 8;
            const float* p =
                (k0 < 64)  ? (seg0 + k0) :
                (k0 < 128) ? (seg1 + (k0 - 64)) :
                (k0 < 192) ? (seg2 + (k0 - 128)) :
                             (seg3 + (k0 - 192));
            float4 f0 = *(const float4*)p;
            float4 f1 = *(const float4*)(p + 4);
            bf16x8 a;
            a[0] = (__bf16)f0.x; a[1] = (__bf16)f0.y;
            a[2] = (__bf16)f0.z; a[3] = (__bf16)f0.w;
            a[4] = (__bf16)f1.x; a[5] = (__bf16)f1.y;
            a[6] = (__bf16)f1.z; a[7] = (__bf16)f1.w;
            #pragma unroll
            for (int nf = 0; nf < 4; ++nf) {
                bf16x8 b = *(const bf16x8*)(sW1 + (nf * 16 + l15) * 512 +
                                            ((kk * 64 + lk * 16) ^ wxor));
                acc[nf] = __builtin_amdgcn_mfma_f32_16x16x32_bf16(a, b, acc[nf], 0, 0, 0);
            }
        }

        // ---- LeakyReLU(0.1) -> bf16 -> sH1 (D: row=lk*4+r, col=nf*16+l15) ----
        #pragma unroll
        for (int nf = 0; nf < 4; ++nf)
            #pragma unroll
            for (int r = 0; r < 4; ++r) {
                float v = acc[nf][r];
                v = fmaxf(v, 0.1f * v);
                sH1[wave][lk * 4 + r][nf * 16 + l15] = (__bf16)v;
            }
        // same-wave LDS RAW: compiler inserts lgkmcnt wait

        // ---- GEMM2^T: O^T = W2^T x H1^T; W2^T frags direct from ws (L1-hot) ----
        f32x4 acc2[4];
        #pragma unroll
        for (int mf = 0; mf < 4; ++mf) acc2[mf] = bias2frag[mf];
        #pragma unroll
        for (int kk2 = 0; kk2 < 2; ++kk2) {
            bf16x8 bh = *(const bf16x8*)&sH1[wave][l15][kk2 * 32 + lk * 8];
            #pragma unroll
            for (int mf = 0; mf < 4; ++mf) {
                bf16x8 aw = *(const bf16x8*)(wsW2 + (mf * 16 + l15) * 64 +
                                             kk2 * 32 + lk * 8);
                acc2[mf] = __builtin_amdgcn_mfma_f32_16x16x32_bf16(aw, bh, acc2[mf], 0, 0, 0);
            }
        }

        // ---- store: lane holds out[e][mf*16+lk*4 .. +3] -> 4x float4 ----
        float* orow = out + (long long)e * 64;
        #pragma unroll
        for (int mf = 0; mf < 4; ++mf)
            *(f32x4*)&orow[mf * 16 + lk * 4] = acc2[mf];
    }
}

extern "C" void kernel_launch(void* const* d_in, const int* in_sizes, int n_in,
                              void* d_out, int out_size, void* d_ws, size_t ws_size,
                              hipStream_t stream) {
    const float* x_s        = (const float*)d_in[0];
    const float* x_t        = (const float*)d_in[1];
    const int*   edge_index = (const int*)d_in[2];   // harness: integer -> int32
    const float* edge_attr  = (const float*)d_in[3];
    const float* u          = (const float*)d_in[4];
    const int*   batch_e    = (const int*)d_in[5];
    const float* W1         = (const float*)d_in[6];
    const float* b1         = (const float*)d_in[7];
    const float* W2         = (const float*)d_in[8];
    const float* b2         = (const float*)d_in[9];
    float*       out        = (float*)d_out;
    __bf16*      wsW2       = (__bf16*)d_ws;         // 8 KB

    prep_w2<<<16, 256, 0, stream>>>(W2, wsW2);

    const int nblocks = (N_TILES + TILES_PER_BLOCK - 1) / TILES_PER_BLOCK; // 1563
    edge_mlp_kernel<<<nblocks, 512, 0, stream>>>(
        x_s, x_t, edge_index, edge_attr, u, batch_e, W1, b1, wsW2, b2, out);
}

// Round 9
// 155.821 us; speedup vs baseline: 1.5499x; 1.5499x over previous
//
#include <hip/hip_runtime.h>
#include <hip/hip_bf16.h>

typedef __attribute__((ext_vector_type(8))) __bf16 bf16x8;
typedef __attribute__((ext_vector_type(4))) float f32x4;

#define N_NODES 50000
#define N_EDGES 800000
#define N_TILES 50000            // 16-edge tiles
#define WAVES 4                  // 256-thread blocks (best-measured r2 config)
#define TPW 8
#define TILES_PER_BLOCK (WAVES * TPW)   // 32

#define XS_OFF 0LL
#define XT_OFF 3200000LL         // 50000*64
#define U_OFF  6400000LL
#define WS_ELEMS 6408192LL       // + 128*64
#define WS_BYTES (WS_ELEMS * 2)

// ---- prep: convert gather tables x_s | x_t | u to bf16 in ws ----
__global__ void prep_tables(const float* __restrict__ x_s,
                            const float* __restrict__ x_t,
                            const float* __restrict__ ug,
                            __bf16* __restrict__ ws) {
    long long i = (long long)(blockIdx.x * 256 + threadIdx.x) * 8;
    if (i >= WS_ELEMS) return;
    const float* src = (i < XT_OFF) ? (x_s + i)
                     : (i < U_OFF)  ? (x_t + (i - XT_OFF))
                                    : (ug  + (i - U_OFF));
    float4 f0 = *(const float4*)src;
    float4 f1 = *(const float4*)(src + 4);
    bf16x8 o;
    o[0] = (__bf16)f0.x; o[1] = (__bf16)f0.y; o[2] = (__bf16)f0.z; o[3] = (__bf16)f0.w;
    o[4] = (__bf16)f1.x; o[5] = (__bf16)f1.y; o[6] = (__bf16)f1.z; o[7] = (__bf16)f1.w;
    *(bf16x8*)(ws + i) = o;
}

template<bool BF>
__global__ __launch_bounds__(256) void edge_mlp_kernel(
    const float* __restrict__ x_s, const float* __restrict__ x_t,
    const int* __restrict__ edge_index, const float* __restrict__ edge_attr,
    const float* __restrict__ ug, const int* __restrict__ batch_e,
    const float* __restrict__ W1, const float* __restrict__ b1,
    const float* __restrict__ W2, const float* __restrict__ b2,
    const __bf16* __restrict__ tbl,   // bf16 tables in ws (BF mode)
    float* __restrict__ out)
{
    // LDS: 32768 + 8192 + 4*2432 = 50688 B -> 3 blocks/CU (12 waves/CU)
    __shared__ __align__(16) unsigned char sW1[32768];   // [n1][k] bf16, 512B rows, XOR-swz
    __shared__ __align__(16) unsigned char sW2[8192];    // [n2][n1] bf16, 128B rows, XOR-swz
    __shared__ __align__(16) __bf16 sH1[WAVES][16][76];  // [edge][n1], pad 76

    const int t = threadIdx.x;

    for (int idx = t; idx < 256 * 64; idx += 256) {
        int k = idx >> 6, n = idx & 63;
        *(__bf16*)(sW1 + n * 512 + ((k * 2) ^ ((n & 7) << 4))) = (__bf16)W1[idx];
    }
    for (int idx = t; idx < 64 * 64; idx += 256) {
        int k = idx >> 6, n = idx & 63;
        *(__bf16*)(sW2 + n * 128 + ((k * 2) ^ ((n & 7) << 4))) = (__bf16)W2[idx];
    }
    __syncthreads();

    const int wave = t >> 6;
    const int lane = t & 63;
    const int l15  = lane & 15;
    const int lk   = lane >> 4;
    const int wxor = (l15 & 7) << 4;

    float bv1[4];
    #pragma unroll
    for (int nf = 0; nf < 4; ++nf) bv1[nf] = b1[nf * 16 + l15];
    f32x4 bias2frag[4];
    #pragma unroll
    for (int mf = 0; mf < 4; ++mf)
        #pragma unroll
        for (int r = 0; r < 4; ++r)
            bias2frag[mf][r] = b2[mf * 16 + lk * 4 + r];

    const int tile_base = (blockIdx.x * WAVES + wave) * TPW;

    int srcs[TPW], tgts[TPW], bgs[TPW];
    #pragma unroll
    for (int i = 0; i < TPW; ++i) {
        const int tile = tile_base + i;
        if (tile < N_TILES) {
            const int e = tile * 16 + l15;
            srcs[i] = edge_index[e];
            tgts[i] = edge_index[N_EDGES + e];
            bgs[i]  = batch_e[e];
        } else { srcs[i] = 0; tgts[i] = 0; bgs[i] = 0; }
    }

    for (int i = 0; i < TPW; ++i) {
        const int tile = tile_base + i;
        if (tile >= N_TILES) break;
        const int e = tile * 16 + l15;

        f32x4 acc[4];
        #pragma unroll
        for (int nf = 0; nf < 4; ++nf)
            acc[nf] = (f32x4){bv1[nf], bv1[nf], bv1[nf], bv1[nf]};

        #pragma unroll
        for (int kk = 0; kk < 8; ++kk) {
            const int k0 = kk * 32 + lk * 8;
            bf16x8 a;
            if (BF) {
                if (kk < 6 && kk >= 4) {        // edge_attr fp32 (contiguous)
                    const float* p = edge_attr + (long long)e * 64 + (k0 - 128);
                    float4 f0 = *(const float4*)p;
                    float4 f1 = *(const float4*)(p + 4);
                    a[0] = (__bf16)f0.x; a[1] = (__bf16)f0.y;
                    a[2] = (__bf16)f0.z; a[3] = (__bf16)f0.w;
                    a[4] = (__bf16)f1.x; a[5] = (__bf16)f1.y;
                    a[6] = (__bf16)f1.z; a[7] = (__bf16)f1.w;
                } else {
                    const __bf16* p =
                        (kk < 2) ? (tbl + XS_OFF + (long long)srcs[i] * 64 + k0) :
                        (kk < 4) ? (tbl + XT_OFF + (long long)tgts[i] * 64 + (k0 - 64)) :
                                   (tbl + U_OFF  + (long long)bgs[i]  * 64 + (k0 - 192));
                    a = *(const bf16x8*)p;       // 16 B, one line per row
                }
            } else {
                const float* p =
                    (k0 < 64)  ? (x_s + (long long)srcs[i] * 64 + k0) :
                    (k0 < 128) ? (x_t + (long long)tgts[i] * 64 + (k0 - 64)) :
                    (k0 < 192) ? (edge_attr + (long long)e * 64 + (k0 - 128)) :
                                 (ug + (long long)bgs[i] * 64 + (k0 - 192));
                float4 f0 = *(const float4*)p;
                float4 f1 = *(const float4*)(p + 4);
                a[0] = (__bf16)f0.x; a[1] = (__bf16)f0.y;
                a[2] = (__bf16)f0.z; a[3] = (__bf16)f0.w;
                a[4] = (__bf16)f1.x; a[5] = (__bf16)f1.y;
                a[6] = (__bf16)f1.z; a[7] = (__bf16)f1.w;
            }
            #pragma unroll
            for (int nf = 0; nf < 4; ++nf) {
                bf16x8 b = *(const bf16x8*)(sW1 + (nf * 16 + l15) * 512 +
                                            ((kk * 64 + lk * 16) ^ wxor));
                acc[nf] = __builtin_amdgcn_mfma_f32_16x16x32_bf16(a, b, acc[nf], 0, 0, 0);
            }
        }

        // ---- LeakyReLU(0.1) -> bf16 -> sH1 ----
        #pragma unroll
        for (int nf = 0; nf < 4; ++nf)
            #pragma unroll
            for (int r = 0; r < 4; ++r) {
                float v = acc[nf][r];
                v = fmaxf(v, 0.1f * v);
                sH1[wave][lk * 4 + r][nf * 16 + l15] = (__bf16)v;
            }

        // ---- GEMM2^T: O^T = W2^T x H1^T ----
        f32x4 acc2[4];
        #pragma unroll
        for (int mf = 0; mf < 4; ++mf) acc2[mf] = bias2frag[mf];
        #pragma unroll
        for (int kk2 = 0; kk2 < 2; ++kk2) {
            bf16x8 bh = *(const bf16x8*)&sH1[wave][l15][kk2 * 32 + lk * 8];
            #pragma unroll
            for (int mf = 0; mf < 4; ++mf) {
                bf16x8 aw = *(const bf16x8*)(sW2 + (mf * 16 + l15) * 128 +
                                             ((kk2 * 64 + lk * 16) ^ wxor));
                acc2[mf] = __builtin_amdgcn_mfma_f32_16x16x32_bf16(aw, bh, acc2[mf], 0, 0, 0);
            }
        }

        float* orow = out + (long long)e * 64;
        #pragma unroll
        for (int mf = 0; mf < 4; ++mf)
            *(f32x4*)&orow[mf * 16 + lk * 4] = acc2[mf];
    }
}

extern "C" void kernel_launch(void* const* d_in, const int* in_sizes, int n_in,
                              void* d_out, int out_size, void* d_ws, size_t ws_size,
                              hipStream_t stream) {
    const float* x_s        = (const float*)d_in[0];
    const float* x_t        = (const float*)d_in[1];
    const int*   edge_index = (const int*)d_in[2];   // harness: integer -> int32
    const float* edge_attr  = (const float*)d_in[3];
    const float* ug         = (const float*)d_in[4];
    const int*   batch_e    = (const int*)d_in[5];
    const float* W1         = (const float*)d_in[6];
    const float* b1         = (const float*)d_in[7];
    const float* W2         = (const float*)d_in[8];
    const float* b2         = (const float*)d_in[9];
    float*       out        = (float*)d_out;

    const int nblocks = (N_TILES + TILES_PER_BLOCK - 1) / TILES_PER_BLOCK; // 1563

    if (ws_size >= (size_t)WS_BYTES) {
        __bf16* tbl = (__bf16*)d_ws;
        prep_tables<<<(int)((WS_ELEMS / 8 + 255) / 256), 256, 0, stream>>>(x_s, x_t, ug, tbl);
        edge_mlp_kernel<true><<<nblocks, 256, 0, stream>>>(
            x_s, x_t, edge_index, edge_attr, ug, batch_e, W1, b1, W2, b2, tbl, out);
    } else {
        edge_mlp_kernel<false><<<nblocks, 256, 0, stream>>>(
            x_s, x_t, edge_index, edge_attr, ug, batch_e, W1, b1, W2, b2, nullptr, out);
    }
}

// Round 10
// 134.428 us; speedup vs baseline: 1.7965x; 1.1591x over previous
//
#include <hip/hip_runtime.h>
#include <hip/hip_bf16.h>

typedef __attribute__((ext_vector_type(8))) __bf16 bf16x8;
typedef __attribute__((ext_vector_type(4))) float f32x4;

#define N_NODES 50000
#define N_EDGES 800000
#define N_TILES 50000            // 16-edge tiles
#define WAVES 4                  // 256-thread blocks
#define TPW 5
#define NBLOCKS 2500             // 2500 * 4 * 5 = 50000 exactly

#define XS_OFF 0LL
#define XT_OFF 3200000LL         // 50000*64
#define U_OFF  6400000LL
#define WS_ELEMS 6408192LL       // + 128*64
#define WS_BYTES (WS_ELEMS * 2)

// ---- prep: convert gather tables x_s | x_t | u to bf16 in ws (r9-verified) ----
__global__ void prep_tables(const float* __restrict__ x_s,
                            const float* __restrict__ x_t,
                            const float* __restrict__ ug,
                            __bf16* __restrict__ ws) {
    long long i = (long long)(blockIdx.x * 256 + threadIdx.x) * 8;
    if (i >= WS_ELEMS) return;
    const float* src = (i < XT_OFF) ? (x_s + i)
                     : (i < U_OFF)  ? (x_t + (i - XT_OFF))
                                    : (ug  + (i - U_OFF));
    float4 f0 = *(const float4*)src;
    float4 f1 = *(const float4*)(src + 4);
    bf16x8 o;
    o[0] = (__bf16)f0.x; o[1] = (__bf16)f0.y; o[2] = (__bf16)f0.z; o[3] = (__bf16)f0.w;
    o[4] = (__bf16)f1.x; o[5] = (__bf16)f1.y; o[6] = (__bf16)f1.z; o[7] = (__bf16)f1.w;
    *(bf16x8*)(ws + i) = o;
}

__device__ __forceinline__ void gload16(const void* g, void* l) {
    __builtin_amdgcn_global_load_lds(
        (const __attribute__((address_space(1))) void*)g,
        (__attribute__((address_space(3))) void*)l, 16, 0, 0);
}

template<bool BF>
__global__ __launch_bounds__(256, 2) void edge_mlp_kernel(
    const float* __restrict__ x_s, const float* __restrict__ x_t,
    const int* __restrict__ edge_index, const float* __restrict__ edge_attr,
    const float* __restrict__ ug, const int* __restrict__ batch_e,
    const float* __restrict__ W1, const float* __restrict__ b1,
    const float* __restrict__ W2, const float* __restrict__ b2,
    const __bf16* __restrict__ tbl,
    float* __restrict__ out)
{
    // LDS: 32768 + 9728 + 32768 = 75264 B -> 2 blocks/CU
    __shared__ __align__(16) unsigned char sW1[32768];     // [n1][k] bf16, 512B rows, XOR-swz
    __shared__ __align__(16) __bf16 sH1[WAVES][16][76];    // [edge][n1], pad 76
    __shared__ __align__(16) unsigned char sRing[WAVES][2][4096]; // per-wave DMA ring

    const int t = threadIdx.x;

    for (int idx = t; idx < 256 * 64; idx += 256) {
        int k = idx >> 6, n = idx & 63;
        *(__bf16*)(sW1 + n * 512 + ((k * 2) ^ ((n & 7) << 4))) = (__bf16)W1[idx];
    }
    __syncthreads();

    const int wave = t >> 6;
    const int lane = t & 63;
    const int l15  = lane & 15;
    const int lk   = lane >> 4;
    const int wxor = (l15 & 7) << 4;

    // ---- bias registers ----
    float bv1[4];
    #pragma unroll
    for (int nf = 0; nf < 4; ++nf) bv1[nf] = b1[nf * 16 + l15];
    f32x4 bias2frag[4];
    #pragma unroll
    for (int mf = 0; mf < 4; ++mf)
        #pragma unroll
        for (int r = 0; r < 4; ++r)
            bias2frag[mf][r] = b2[mf * 16 + lk * 4 + r];

    // ---- hoist W2^T A-fragments into 16 VGPRs (tile-invariant) ----
    // aw2[kk2][mf] elem r = W2[(kk2*32+lk*8+r)][mf*16+l15]
    bf16x8 aw2[2][4];
    #pragma unroll
    for (int kk2 = 0; kk2 < 2; ++kk2)
        #pragma unroll
        for (int mf = 0; mf < 4; ++mf)
            #pragma unroll
            for (int r = 0; r < 8; ++r)
                aw2[kk2][mf][r] = (__bf16)W2[(kk2 * 32 + lk * 8 + r) * 64 + mf * 16 + l15];

    const int tile_base = (blockIdx.x * WAVES + wave) * TPW;

    // ---- preload indices; build shfl'd per-DMA-lane indices ----
    int srcs[TPW], tgts[TPW], bgs[TPW];
    int ss_lo[TPW], ss_hi[TPW], tt_lo[TPW], tt_hi[TPW];
    #pragma unroll
    for (int i = 0; i < TPW; ++i) {
        const int e = (tile_base + i) * 16 + l15;
        srcs[i] = edge_index[e];
        tgts[i] = edge_index[N_EDGES + e];
        bgs[i]  = batch_e[e];
    }
    #pragma unroll
    for (int i = 0; i < TPW; ++i) {
        ss_lo[i] = __shfl(srcs[i], lane >> 3);
        ss_hi[i] = __shfl(srcs[i], 8 + (lane >> 3));
        tt_lo[i] = __shfl(tgts[i], lane >> 3);
        tt_hi[i] = __shfl(tgts[i], 8 + (lane >> 3));
    }
    // pre-swizzled source elem offset (bank swizzle applied at DMA source; rule 21)
    const int swzel = ((((lane & 7) << 4) ^ (((lane >> 3) & 7) << 4)) >> 1);

    // ---- prologue: DMA tile 0 into buf 0 ----
    if (BF) {
        unsigned char* rb = &sRing[wave][0][0];
        gload16(tbl + XS_OFF + (long long)ss_lo[0] * 64 + swzel, rb);
        gload16(tbl + XS_OFF + (long long)ss_hi[0] * 64 + swzel, rb + 1024);
        gload16(tbl + XT_OFF + (long long)tt_lo[0] * 64 + swzel, rb + 2048);
        gload16(tbl + XT_OFF + (long long)tt_hi[0] * 64 + swzel, rb + 3072);
    }

    #pragma unroll
    for (int i = 0; i < TPW; ++i) {
        const int tile = tile_base + i;
        const int e = tile * 16 + l15;

        // ---- (a) edge_attr (fp32, contiguous) + u (bf16 tbl) loads, pinned ----
        const float* epl = edge_attr + (long long)e * 64 + lk * 8;
        float4 ef0 = *(const float4*)(epl);
        float4 ef1 = *(const float4*)(epl + 4);
        float4 ef2 = *(const float4*)(epl + 32);
        float4 ef3 = *(const float4*)(epl + 36);
        bf16x8 uf0, uf1;
        if (BF) {
            const __bf16* up = tbl + U_OFF + (long long)bgs[i] * 64 + lk * 8;
            uf0 = *(const bf16x8*)(up);
            uf1 = *(const bf16x8*)(up + 32);
        } else {
            const float* up = ug + (long long)bgs[i] * 64 + lk * 8;
            float4 g0 = *(const float4*)(up),      g1 = *(const float4*)(up + 4);
            float4 g2 = *(const float4*)(up + 32), g3 = *(const float4*)(up + 36);
            #pragma unroll
            for (int r = 0; r < 4; ++r) {
                uf0[r] = (__bf16)((const float*)&g0)[r]; uf0[4+r] = (__bf16)((const float*)&g1)[r];
                uf1[r] = (__bf16)((const float*)&g2)[r]; uf1[4+r] = (__bf16)((const float*)&g3)[r];
            }
        }
        if (BF) __builtin_amdgcn_sched_barrier(0);

        // ---- (b) DMA prefetch tile i+1 into buf (i+1)&1 ----
        if (BF && (i + 1 < TPW)) {
            unsigned char* rb = &sRing[wave][(i + 1) & 1][0];
            gload16(tbl + XS_OFF + (long long)ss_lo[i+1] * 64 + swzel, rb);
            gload16(tbl + XS_OFF + (long long)ss_hi[i+1] * 64 + swzel, rb + 1024);
            gload16(tbl + XT_OFF + (long long)tt_lo[i+1] * 64 + swzel, rb + 2048);
            gload16(tbl + XT_OFF + (long long)tt_hi[i+1] * 64 + swzel, rb + 3072);
        }

        // ---- (c) wait for tile i's DMA (in-order vmcnt; J = younger ops) ----
        if (BF) {
            if (i == 0 || i == TPW - 1) asm volatile("s_waitcnt vmcnt(10)" ::: "memory");
            else                        asm volatile("s_waitcnt vmcnt(14)" ::: "memory");
            __builtin_amdgcn_sched_barrier(0);
        }

        // ---- (d) GEMM1: kk0-3 from ring, kk4-5 from edge_attr, kk6-7 from u ----
        f32x4 acc[4];
        #pragma unroll
        for (int nf = 0; nf < 4; ++nf)
            acc[nf] = (f32x4){bv1[nf], bv1[nf], bv1[nf], bv1[nf]};

        #pragma unroll
        for (int kk = 0; kk < 8; ++kk) {
            bf16x8 a;
            if (kk < 4) {
                if (BF) {
                    const int tb = kk >> 1, kseg = kk & 1;
                    const int byte = tb * 2048 + l15 * 128 +
                                     ((kseg * 64 + lk * 16) ^ ((l15 & 7) << 4));
                    a = *(const bf16x8*)&sRing[wave][i & 1][byte];
                } else {
                    const int k0 = kk * 32 + lk * 8;
                    const float* p = (k0 < 64) ? (x_s + (long long)srcs[i] * 64 + k0)
                                               : (x_t + (long long)tgts[i] * 64 + (k0 - 64));
                    float4 f0 = *(const float4*)p;
                    float4 f1 = *(const float4*)(p + 4);
                    a[0]=(__bf16)f0.x; a[1]=(__bf16)f0.y; a[2]=(__bf16)f0.z; a[3]=(__bf16)f0.w;
                    a[4]=(__bf16)f1.x; a[5]=(__bf16)f1.y; a[6]=(__bf16)f1.z; a[7]=(__bf16)f1.w;
                }
            } else if (kk == 4) {
                a[0]=(__bf16)ef0.x; a[1]=(__bf16)ef0.y; a[2]=(__bf16)ef0.z; a[3]=(__bf16)ef0.w;
                a[4]=(__bf16)ef1.x; a[5]=(__bf16)ef1.y; a[6]=(__bf16)ef1.z; a[7]=(__bf16)ef1.w;
            } else if (kk == 5) {
                a[0]=(__bf16)ef2.x; a[1]=(__bf16)ef2.y; a[2]=(__bf16)ef2.z; a[3]=(__bf16)ef2.w;
                a[4]=(__bf16)ef3.x; a[5]=(__bf16)ef3.y; a[6]=(__bf16)ef3.z; a[7]=(__bf16)ef3.w;
            } else {
                a = (kk == 6) ? uf0 : uf1;
            }
            #pragma unroll
            for (int nf = 0; nf < 4; ++nf) {
                bf16x8 b = *(const bf16x8*)(sW1 + (nf * 16 + l15) * 512 +
                                            ((kk * 64 + lk * 16) ^ wxor));
                acc[nf] = __builtin_amdgcn_mfma_f32_16x16x32_bf16(a, b, acc[nf], 0, 0, 0);
            }
        }

        // ---- (e) LeakyReLU(0.1) -> bf16 -> sH1 ----
        #pragma unroll
        for (int nf = 0; nf < 4; ++nf)
            #pragma unroll
            for (int r = 0; r < 4; ++r) {
                float v = acc[nf][r];
                v = fmaxf(v, 0.1f * v);
                sH1[wave][lk * 4 + r][nf * 16 + l15] = (__bf16)v;
            }

        // ---- (f) GEMM2^T: O^T = W2^T x H1^T (aw2 in registers) ----
        f32x4 acc2[4];
        #pragma unroll
        for (int mf = 0; mf < 4; ++mf) acc2[mf] = bias2frag[mf];
        #pragma unroll
        for (int kk2 = 0; kk2 < 2; ++kk2) {
            bf16x8 bh = *(const bf16x8*)&sH1[wave][l15][kk2 * 32 + lk * 8];
            #pragma unroll
            for (int mf = 0; mf < 4; ++mf)
                acc2[mf] = __builtin_amdgcn_mfma_f32_16x16x32_bf16(aw2[kk2][mf], bh, acc2[mf], 0, 0, 0);
        }

        // ---- (g) store: lane holds out[e][mf*16+lk*4 .. +3] ----
        float* orow = out + (long long)e * 64;
        #pragma unroll
        for (int mf = 0; mf < 4; ++mf)
            *(f32x4*)&orow[mf * 16 + lk * 4] = acc2[mf];
    }
}

extern "C" void kernel_launch(void* const* d_in, const int* in_sizes, int n_in,
                              void* d_out, int out_size, void* d_ws, size_t ws_size,
                              hipStream_t stream) {
    const float* x_s        = (const float*)d_in[0];
    const float* x_t        = (const float*)d_in[1];
    const int*   edge_index = (const int*)d_in[2];   // harness: integer -> int32
    const float* edge_attr  = (const float*)d_in[3];
    const float* ug         = (const float*)d_in[4];
    const int*   batch_e    = (const int*)d_in[5];
    const float* W1         = (const float*)d_in[6];
    const float* b1         = (const float*)d_in[7];
    const float* W2         = (const float*)d_in[8];
    const float* b2         = (const float*)d_in[9];
    float*       out        = (float*)d_out;

    if (ws_size >= (size_t)WS_BYTES) {
        __bf16* tbl = (__bf16*)d_ws;
        prep_tables<<<(int)((WS_ELEMS / 8 + 255) / 256), 256, 0, stream>>>(x_s, x_t, ug, tbl);
        edge_mlp_kernel<true><<<NBLOCKS, 256, 0, stream>>>(
            x_s, x_t, edge_index, edge_attr, ug, batch_e, W1, b1, W2, b2, tbl, out);
    } else {
        edge_mlp_kernel<false><<<NBLOCKS, 256, 0, stream>>>(
            x_s, x_t, edge_index, edge_attr, ug, batch_e, W1, b1, W2, b2, nullptr, out);
    }
}